// Round 14
// baseline (141.813 us; speedup 1.0000x reference)
//
#include <hip/hip_runtime.h>
#include <math.h>

#define BSZ 8
#define HH 480
#define WW 640
#define NPIX (HH*WW)          // 307200
#define VRES 100
#define NZB 80
#define NVOXB (VRES*VRES*NZB) // 800000
#define LM 480

// output layout (flat float32, return order)
#define OFF_COORDS 0LL
#define OFF_FEAT   9830400LL
#define OFF_MAPS   29491200LL
#define OFF_POSES  36864000LL
#define OFF_REP    36864024LL

typedef float fx4 __attribute__((ext_vector_type(4)));
typedef int   ix4 __attribute__((ext_vector_type(4)));

struct PtRes { float depth, X, Z; int g0, g1, g2, vox; bool valid; };

__device__ __forceinline__ int voxid(int c0, int c1, int c2) {
  return (c2 * VRES + c0) * VRES + c1;   // (c2,c0) near-constant per wave
}

// PASSING arithmetic chain (round 6) — do not perturb.
__device__ __forceinline__ PtRes compute_pt(float draw, int u, int r, float rfoc) {
  PtRes p;
  p.depth = __fmul_rn(draw, 0.01f);
  p.X = __fadd_rn(__fmul_rn(__fmul_rn(__fsub_rn((float)u, 319.5f), p.depth), rfoc), 2.5f);
  p.Z = __fadd_rn(__fmul_rn(__fmul_rn(__fsub_rn((float)(HH - 1 - r), 239.5f), p.depth), rfoc), 0.88f);
  p.valid = (p.X > 0.0f) & (p.X < 5.0f) & (p.depth > 0.0f) & (p.depth < 5.0f)
          & (p.Z > -0.4f) & (p.Z < 3.6f);
  p.g0 = (int)floorf(__fmul_rn(p.X, 20.0f));
  p.g1 = (int)floorf(__fmul_rn(p.depth, 20.0f));
  p.g2 = (int)floorf(__fmul_rn(p.Z, 20.0f));
  int c0 = min(max(p.g0, 0), VRES - 1);
  int c1 = min(max(p.g1, 0), VRES - 1);
  int c2 = min(max(p.g2 + 8, 0), NZB - 1);
  p.vox = voxid(c0, c1, c2);
  return p;
}

__device__ __forceinline__ void pose_calc(int b, const float* pose_obs,
                                          const float* poses_last,
                                          float* out_poses, float* params) {
  float p0 = poses_last[b*3+0], p1 = poses_last[b*3+1], p2 = poses_last[b*3+2];
  float r0 = pose_obs[b*3+0],  r1 = pose_obs[b*3+1],  r2 = pose_obs[b*3+2];
  const float DEGf = (float)57.29577951308232;
  float thf = __fmul_rn(p2, (float)0.017453292519943295);
  float sth = (float)sin((double)thf);
  float cth = (float)cos((double)thf);
  float y = __fadd_rn(__fadd_rn(p1, __fmul_rn(r0, sth)), __fmul_rn(r1, cth));
  float x = __fsub_rn(__fadd_rn(p0, __fmul_rn(r0, cth)), __fmul_rn(r1, sth));
  float t = __fadd_rn(p2, __fmul_rn(r2, DEGf));
  t = __fadd_rn(fmodf(__fsub_rn(t, 180.0f), 360.0f), 180.0f);
  t = __fsub_rn(fmodf(__fadd_rn(t, 180.0f), 360.0f), 180.0f);
  out_poses[b*3+0] = x; out_poses[b*3+1] = y; out_poses[b*3+2] = t;
  float st0 = __fmul_rn(__fmul_rn(x, 100.0f), 0.2f);
  float st1 = __fmul_rn(__fmul_rn(y, 100.0f), 0.2f);
  float st2 = __fsub_rn(90.0f, t);
  float trad = __fmul_rn(st2, (float)(M_PI / 180.0));
  params[b*4+0] = (float)cos((double)trad);
  params[b*4+1] = (float)sin((double)trad);
  params[b*4+2] = st1;
  params[b*4+3] = st0;
}

#define VPT 8
#define TPB_ROWS (NPIX / VPT)          // 38400 threads per batch
#define VOXBLK (BSZ * TPB_ROWS / 256)  // 1200 blocks
#define NC (BSZ * 4 * LM * LM / 4)     // 1,843,200 float4 copies
#define NCBLK (NC / 256)
#define NIB4 (NVOXB / 4)               // 200000 int4 per batch
#define IBPB ((NIB4 + 255) / 256)      // 782 init blocks per batch

// kernel 1: pose + XCD-pinned CACHED init of first[] — wave writes 1KiB
// contiguous (full L2 lines, no RMW fetch), leaving each batch's 3.2 MB slice
// dirty + resident in its XCD's L2 for the following passes.
__global__ __launch_bounds__(256) void init_pose(int* __restrict__ first,
                                                 const float* __restrict__ pose_obs,
                                                 const float* __restrict__ poses_last,
                                                 float* __restrict__ out_poses,
                                                 float* __restrict__ params) {
  if (blockIdx.x == 0 && threadIdx.x < BSZ)
    pose_calc(threadIdx.x, pose_obs, poses_last, out_poses, params);
  int b = blockIdx.x & 7;
  int j = (blockIdx.x >> 3) * 256 + threadIdx.x;
  if (j < NIB4)
    *(ix4*)(first + (size_t)b * NVOXB + (size_t)j * 4) =
        (ix4){0x7FFFFFFF, 0x7FFFFFFF, 0x7FFFFFFF, 0x7FFFFFFF};
}

// kernel 2: racy candidate stores (hit the L2-resident init lines).
// obs loads NT to avoid evicting first[].
__global__ __launch_bounds__(256) void vox_store(const float* __restrict__ obs,
                                                 int* __restrict__ first, float rfoc) {
  int b   = blockIdx.x & 7;
  int t   = (blockIdx.x >> 3) * 256 + threadIdx.x;
  int n0 = t * VPT;
  int r = n0 / WW, u0 = n0 % WW;
  const float* rowp = obs + ((size_t)(b*4 + 3) * HH + r) * WW + u0;
  fx4 da = __builtin_nontemporal_load((const fx4*)rowp);
  fx4 db = __builtin_nontemporal_load((const fx4*)(rowp + 4));
  float dv[VPT] = {da.x, da.y, da.z, da.w, db.x, db.y, db.z, db.w};
  int* fb = first + b * NVOXB;
  #pragma unroll
  for (int k = 0; k < VPT; ++k) {
    PtRes p = compute_pt(dv[k], u0 + k, r, rfoc);
    if (p.valid) fb[p.vox] = n0 + k;
  }
}

// kernel 3: refine (atomic only when beating stored candidate) + NT map copy.
__global__ __launch_bounds__(256) void vox_refine_copy(const float* __restrict__ obs,
                                                       int* __restrict__ first, float rfoc,
                                                       const float* __restrict__ map_last,
                                                       float* __restrict__ out_maps,
                                                       int do_copy) {
  int bid = blockIdx.x;
  if (bid < VOXBLK) {
    int b = bid & 7;
    int t = (bid >> 3) * 256 + threadIdx.x;
    int n0 = t * VPT;
    int r = n0 / WW, u0 = n0 % WW;
    const float* rowp = obs + ((size_t)(b*4 + 3) * HH + r) * WW + u0;
    fx4 da = __builtin_nontemporal_load((const fx4*)rowp);
    fx4 db = __builtin_nontemporal_load((const fx4*)(rowp + 4));
    float dv[VPT] = {da.x, da.y, da.z, da.w, db.x, db.y, db.z, db.w};
    int* fb = first + b * NVOXB;
    #pragma unroll
    for (int k = 0; k < VPT; ++k) {
      PtRes p = compute_pt(dv[k], u0 + k, r, rfoc);
      if (p.valid) {
        int n = n0 + k;
        if (n < fb[p.vox]) atomicMin(&fb[p.vox], n);
      }
    }
  } else if (do_copy) {
    int j = (bid - VOXBLK) * 256 + threadIdx.x;
    if (j < NC) {
      fx4 v = __builtin_nontemporal_load((const fx4*)(map_last + (size_t)j * 4));
      __builtin_nontemporal_store(v, (fx4*)(out_maps + (size_t)j * 4));
    }
  }
}

// kernel 4: fused coords + rep + feats + maps scatter (first[] reads cached/L2-hot)
__global__ __launch_bounds__(256) void fused_kernel(const float* __restrict__ obs,
                                                    const int* __restrict__ first,
                                                    const float* __restrict__ params,
                                                    float* __restrict__ out, float rfoc,
                                                    int write_maps) {
  int b = blockIdx.x & 7;
  int n = (blockIdx.x >> 3) * 256 + threadIdx.x;
  int gid = b * NPIX + n;
  int r = n / WW, u = n % WW;
  float draw = __builtin_nontemporal_load(&obs[((size_t)(b*4 + 3) * HH + r) * WW + u]);
  PtRes p = compute_pt(draw, u, r, rfoc);
  bool rep = p.valid && (first[b * NVOXB + p.vox] == n);

  float c   = params[b*4+0], s = params[b*4+1];
  float tr0 = params[b*4+2], tr1 = params[b*4+3];

  float gcf0 = (float)p.g1, gcf1 = (float)(p.g0 - 50);
  float d0 = fmaf(gcf1, -s, __fmul_rn(gcf0, c));
  float d1 = fmaf(gcf1,  c, __fmul_rn(gcf0, s));
  int gx = (int)rintf(__fadd_rn(d0, tr0));
  int gy = (int)rintf(__fadd_rn(d1, tr1));
  int gz = p.g2 + 8;

  fx4 ncv = rep ? (fx4){(float)b, (float)gx, (float)gy, (float)gz}
                : (fx4){0.f, 0.f, 0.f, 0.f};
  __builtin_nontemporal_store(ncv, (fx4*)(out + OFF_COORDS + (size_t)gid * 4));
  out[OFF_REP + gid] = rep ? 1.0f : 0.0f;

  fx4 f0 = {0.f, 0.f, 0.f, 0.f};
  fx4 f1 = {0.f, 0.f, 0.f, 0.f};
  if (rep) {
    float cf0 = p.depth;
    float cf1 = __fsub_rn(p.X, 2.5f);
    float e0 = __fadd_rn(fmaf(cf1, -s, __fmul_rn(cf0, c)), __fmul_rn(tr0, 0.05f));
    float e1 = __fadd_rn(fmaf(cf1,  c, __fmul_rn(cf0, s)), __fmul_rn(tr1, 0.05f));
    float e2 = __fadd_rn(p.Z, 0.4f);
    float R  = __builtin_nontemporal_load(&obs[((size_t)(b*4 + 0) * HH + r) * WW + u]);
    float G  = __builtin_nontemporal_load(&obs[((size_t)(b*4 + 1) * HH + r) * WW + u]);
    float Bv = __builtin_nontemporal_load(&obs[((size_t)(b*4 + 2) * HH + r) * WW + u]);
    f0 = (fx4){e0, e1, e2, R};
    f1 = (fx4){G, Bv, 0.f, 0.f};
  }
  __builtin_nontemporal_store(f0, (fx4*)(out + OFF_FEAT + (size_t)gid * 8));
  __builtin_nontemporal_store(f1, (fx4*)(out + OFF_FEAT + (size_t)gid * 8 + 4));

  if (write_maps && rep) {
    int xs = min(max(gx, 0), LM - 1);
    int ys = min(max(gy, 0), LM - 1);
    out[OFF_MAPS + ((size_t)(b*4 + 1) * LM + xs) * LM + ys] = 1.0f;
    if (gz >= 13 && gz <= 25)
      out[OFF_MAPS + ((size_t)(b*4 + 0) * LM + xs) * LM + ys] = 1.0f;
  }
}

// ---- fallback-only kernels (first[] aliased into maps region, round-10 path) ----
__global__ void pose_kernel(const float* __restrict__ pose_obs,
                            const float* __restrict__ poses_last,
                            float* __restrict__ out_poses,
                            float* __restrict__ params) {
  int b = threadIdx.x;
  if (b < BSZ) pose_calc(b, pose_obs, poses_last, out_poses, params);
}

__global__ __launch_bounds__(256) void copy_maps(const float* __restrict__ map_last,
                                                 float* __restrict__ out_maps) {
  int i = blockIdx.x * blockDim.x + threadIdx.x;
  if (i < NC)
    *(float4*)(out_maps + (size_t)i * 4) = *(const float4*)(map_last + (size_t)i * 4);
}

__global__ __launch_bounds__(256) void scatter_maps(const float* __restrict__ out_coords,
                                                    const float* __restrict__ rep_flags,
                                                    float* __restrict__ out_maps) {
  int gid = blockIdx.x * blockDim.x + threadIdx.x;
  if (gid >= BSZ * NPIX) return;
  if (rep_flags[gid] == 0.0f) return;
  int b = gid / NPIX;
  float4 nc = *(const float4*)(out_coords + (size_t)gid * 4);
  int gx = (int)nc.y, gy = (int)nc.z, gz = (int)nc.w;
  int xs = min(max(gx, 0), LM - 1);
  int ys = min(max(gy, 0), LM - 1);
  out_maps[((size_t)(b*4 + 1) * LM + xs) * LM + ys] = 1.0f;
  if (gz >= 13 && gz <= 25)
    out_maps[((size_t)(b*4 + 0) * LM + xs) * LM + ys] = 1.0f;
}

extern "C" void kernel_launch(void* const* d_in, const int* in_sizes, int n_in,
                              void* d_out, int out_size, void* d_ws, size_t ws_size,
                              hipStream_t stream) {
  const float* obs        = (const float*)d_in[0];
  const float* pose_obs   = (const float*)d_in[1];
  const float* poses_last = (const float*)d_in[4];
  const float* map_last   = (const float*)d_in[5];
  float* out = (float*)d_out;

  const size_t FIRST_BYTES = (size_t)BSZ * NVOXB * sizeof(int);  // 25.6 MB
  bool use_ws = ws_size >= FIRST_BYTES + 4096;
  float* params = (float*)d_ws;
  int*   first  = use_ws ? (int*)((char*)d_ws + 4096) : (int*)(out + OFF_MAPS);

  float focf = (float)((double)WW / 2.0 / tan(39.5 * (M_PI / 180.0)));
  float rfoc = (float)(1.0 / (double)focf);

  if (use_ws) {
    hipLaunchKernelGGL(init_pose, dim3(8 * IBPB), dim3(256), 0, stream,
                       first, pose_obs, poses_last, out + OFF_POSES, params);
    hipLaunchKernelGGL(vox_store, dim3(VOXBLK), dim3(256), 0, stream, obs, first, rfoc);
    hipLaunchKernelGGL(vox_refine_copy, dim3(VOXBLK + NCBLK), dim3(256), 0, stream,
                       obs, first, rfoc, map_last, out + OFF_MAPS, 1);
    hipLaunchKernelGGL(fused_kernel, dim3(BSZ * NPIX / 256), dim3(256), 0, stream,
                       obs, first, params, out, rfoc, 1);
  } else {
    hipLaunchKernelGGL(pose_kernel, dim3(1), dim3(64), 0, stream,
                       pose_obs, poses_last, out + OFF_POSES, params);
    hipLaunchKernelGGL(vox_store, dim3(VOXBLK), dim3(256), 0, stream, obs, first, rfoc);
    hipLaunchKernelGGL(vox_refine_copy, dim3(VOXBLK), dim3(256), 0, stream,
                       obs, first, rfoc, map_last, out + OFF_MAPS, 0);
    hipLaunchKernelGGL(fused_kernel, dim3(BSZ * NPIX / 256), dim3(256), 0, stream,
                       obs, first, params, out, rfoc, 0);
    hipLaunchKernelGGL(copy_maps, dim3((NC + 255) / 256), dim3(256), 0, stream,
                       map_last, out + OFF_MAPS);
    hipLaunchKernelGGL(scatter_maps, dim3((BSZ * NPIX + 255) / 256), dim3(256), 0, stream,
                       out + OFF_COORDS, out + OFF_REP, out + OFF_MAPS);
  }
}

// Round 15
// 116.981 us; speedup vs baseline: 1.2123x; 1.2123x over previous
//
#include <hip/hip_runtime.h>
#include <math.h>

#define BSZ 8
#define HH 480
#define WW 640
#define NPIX (HH*WW)          // 307200
#define VRES 100
#define NZB 80
#define NVOXB (VRES*VRES*NZB) // 800000
#define LM 480

// output layout (flat float32, return order)
#define OFF_COORDS 0LL
#define OFF_FEAT   9830400LL
#define OFF_MAPS   29491200LL
#define OFF_POSES  36864000LL
#define OFF_REP    36864024LL

typedef float fx4 __attribute__((ext_vector_type(4)));

struct PtRes { float depth, X, Z; int g0, g1, g2, vox; bool valid; };

__device__ __forceinline__ int voxid(int c0, int c1, int c2) {
  return (c2 * VRES + c0) * VRES + c1;
}

// PASSING arithmetic chain (round 6) — do not perturb.
__device__ __forceinline__ PtRes compute_pt(float draw, int u, int r, float rfoc) {
  PtRes p;
  p.depth = __fmul_rn(draw, 0.01f);
  p.X = __fadd_rn(__fmul_rn(__fmul_rn(__fsub_rn((float)u, 319.5f), p.depth), rfoc), 2.5f);
  p.Z = __fadd_rn(__fmul_rn(__fmul_rn(__fsub_rn((float)(HH - 1 - r), 239.5f), p.depth), rfoc), 0.88f);
  p.valid = (p.X > 0.0f) & (p.X < 5.0f) & (p.depth > 0.0f) & (p.depth < 5.0f)
          & (p.Z > -0.4f) & (p.Z < 3.6f);
  p.g0 = (int)floorf(__fmul_rn(p.X, 20.0f));
  p.g1 = (int)floorf(__fmul_rn(p.depth, 20.0f));
  p.g2 = (int)floorf(__fmul_rn(p.Z, 20.0f));
  int c0 = min(max(p.g0, 0), VRES - 1);
  int c1 = min(max(p.g1, 0), VRES - 1);
  int c2 = min(max(p.g2 + 8, 0), NZB - 1);
  p.vox = voxid(c0, c1, c2);
  return p;
}

__device__ __forceinline__ void pose_calc(int b, const float* pose_obs,
                                          const float* poses_last,
                                          float* out_poses, float* params) {
  float p0 = poses_last[b*3+0], p1 = poses_last[b*3+1], p2 = poses_last[b*3+2];
  float r0 = pose_obs[b*3+0],  r1 = pose_obs[b*3+1],  r2 = pose_obs[b*3+2];
  const float DEGf = (float)57.29577951308232;
  float thf = __fmul_rn(p2, (float)0.017453292519943295);
  float sth = (float)sin((double)thf);
  float cth = (float)cos((double)thf);
  float y = __fadd_rn(__fadd_rn(p1, __fmul_rn(r0, sth)), __fmul_rn(r1, cth));
  float x = __fsub_rn(__fadd_rn(p0, __fmul_rn(r0, cth)), __fmul_rn(r1, sth));
  float t = __fadd_rn(p2, __fmul_rn(r2, DEGf));
  t = __fadd_rn(fmodf(__fsub_rn(t, 180.0f), 360.0f), 180.0f);
  t = __fsub_rn(fmodf(__fadd_rn(t, 180.0f), 360.0f), 180.0f);
  out_poses[b*3+0] = x; out_poses[b*3+1] = y; out_poses[b*3+2] = t;
  float st0 = __fmul_rn(__fmul_rn(x, 100.0f), 0.2f);
  float st1 = __fmul_rn(__fmul_rn(y, 100.0f), 0.2f);
  float st2 = __fsub_rn(90.0f, t);
  float trad = __fmul_rn(st2, (float)(M_PI / 180.0));
  params[b*4+0] = (float)cos((double)trad);
  params[b*4+1] = (float)sin((double)trad);
  params[b*4+2] = st1;
  params[b*4+3] = st0;
}

#define VPT 8
#define TPB_ROWS (NPIX / VPT)          // 38400 threads per batch
#define VOXBLK (BSZ * TPB_ROWS / 256)  // 1200 blocks
#define NC (BSZ * 4 * LM * LM / 4)     // 1,843,200 float4 copies
#define NCBLK (NC / 256)

// kernel 1: racy candidate stores (XCD-pinned: batch = blockIdx & 7) + pose on block 0.
// params written here are consumed only by fused_kernel (2 launches later) — safe.
__global__ __launch_bounds__(256) void vox_store_pose(const float* __restrict__ obs,
                                                      int* __restrict__ first, float rfoc,
                                                      const float* __restrict__ pose_obs,
                                                      const float* __restrict__ poses_last,
                                                      float* __restrict__ out_poses,
                                                      float* __restrict__ params) {
  if (blockIdx.x == 0 && threadIdx.x < BSZ)
    pose_calc(threadIdx.x, pose_obs, poses_last, out_poses, params);
  int b   = blockIdx.x & 7;
  int t   = (blockIdx.x >> 3) * 256 + threadIdx.x;
  int n0 = t * VPT;
  int r = n0 / WW, u0 = n0 % WW;
  const float* rowp = obs + ((size_t)(b*4 + 3) * HH + r) * WW + u0;
  float4 da = *(const float4*)(rowp);
  float4 db = *(const float4*)(rowp + 4);
  float dv[VPT] = {da.x, da.y, da.z, da.w, db.x, db.y, db.z, db.w};
  int* fb = first + b * NVOXB;
  #pragma unroll
  for (int k = 0; k < VPT; ++k) {
    PtRes p = compute_pt(dv[k], u0 + k, r, rfoc);
    if (p.valid) fb[p.vox] = n0 + k;
  }
}

// kernel 2: refine (atomic only when beating the stored candidate) + map copy.
__global__ __launch_bounds__(256) void vox_refine_copy(const float* __restrict__ obs,
                                                       int* __restrict__ first, float rfoc,
                                                       const float* __restrict__ map_last,
                                                       float* __restrict__ out_maps,
                                                       int do_copy) {
  int bid = blockIdx.x;
  if (bid < VOXBLK) {
    int b = bid & 7;
    int t = (bid >> 3) * 256 + threadIdx.x;
    int n0 = t * VPT;
    int r = n0 / WW, u0 = n0 % WW;
    const float* rowp = obs + ((size_t)(b*4 + 3) * HH + r) * WW + u0;
    float4 da = *(const float4*)(rowp);
    float4 db = *(const float4*)(rowp + 4);
    float dv[VPT] = {da.x, da.y, da.z, da.w, db.x, db.y, db.z, db.w};
    int* fb = first + b * NVOXB;
    #pragma unroll
    for (int k = 0; k < VPT; ++k) {
      PtRes p = compute_pt(dv[k], u0 + k, r, rfoc);
      if (p.valid) {
        int n = n0 + k;
        if (n < fb[p.vox]) atomicMin(&fb[p.vox], n);
      }
    }
  } else if (do_copy) {
    int j = (bid - VOXBLK) * 256 + threadIdx.x;
    if (j < NC)
      *(float4*)(out_maps + (size_t)j * 4) = *(const float4*)(map_last + (size_t)j * 4);
  }
}

// kernel 3: fused coords + rep + feats (+ maps scatter on ws path)
__global__ __launch_bounds__(256) void fused_kernel(const float* __restrict__ obs,
                                                    const int* __restrict__ first,
                                                    const float* __restrict__ params,
                                                    float* __restrict__ out, float rfoc,
                                                    int write_maps) {
  int b = blockIdx.x & 7;
  int n = (blockIdx.x >> 3) * 256 + threadIdx.x;
  int gid = b * NPIX + n;
  int r = n / WW, u = n % WW;
  float draw = obs[((size_t)(b*4 + 3) * HH + r) * WW + u];
  PtRes p = compute_pt(draw, u, r, rfoc);
  bool rep = p.valid && (first[b * NVOXB + p.vox] == n);

  float c   = params[b*4+0], s = params[b*4+1];
  float tr0 = params[b*4+2], tr1 = params[b*4+3];

  float gcf0 = (float)p.g1, gcf1 = (float)(p.g0 - 50);
  float d0 = fmaf(gcf1, -s, __fmul_rn(gcf0, c));
  float d1 = fmaf(gcf1,  c, __fmul_rn(gcf0, s));
  int gx = (int)rintf(__fadd_rn(d0, tr0));
  int gy = (int)rintf(__fadd_rn(d1, tr1));
  int gz = p.g2 + 8;

  fx4 ncv = rep ? (fx4){(float)b, (float)gx, (float)gy, (float)gz}
                : (fx4){0.f, 0.f, 0.f, 0.f};
  __builtin_nontemporal_store(ncv, (fx4*)(out + OFF_COORDS + (size_t)gid * 4));
  out[OFF_REP + gid] = rep ? 1.0f : 0.0f;

  fx4 f0 = {0.f, 0.f, 0.f, 0.f};
  fx4 f1 = {0.f, 0.f, 0.f, 0.f};
  if (rep) {
    float cf0 = p.depth;
    float cf1 = __fsub_rn(p.X, 2.5f);
    float e0 = __fadd_rn(fmaf(cf1, -s, __fmul_rn(cf0, c)), __fmul_rn(tr0, 0.05f));
    float e1 = __fadd_rn(fmaf(cf1,  c, __fmul_rn(cf0, s)), __fmul_rn(tr1, 0.05f));
    float e2 = __fadd_rn(p.Z, 0.4f);
    float R  = obs[((size_t)(b*4 + 0) * HH + r) * WW + u];
    float G  = obs[((size_t)(b*4 + 1) * HH + r) * WW + u];
    float Bv = obs[((size_t)(b*4 + 2) * HH + r) * WW + u];
    f0 = (fx4){e0, e1, e2, R};
    f1 = (fx4){G, Bv, 0.f, 0.f};
  }
  __builtin_nontemporal_store(f0, (fx4*)(out + OFF_FEAT + (size_t)gid * 8));
  __builtin_nontemporal_store(f1, (fx4*)(out + OFF_FEAT + (size_t)gid * 8 + 4));

  if (write_maps && rep) {
    int xs = min(max(gx, 0), LM - 1);
    int ys = min(max(gy, 0), LM - 1);
    out[OFF_MAPS + ((size_t)(b*4 + 1) * LM + xs) * LM + ys] = 1.0f;
    if (gz >= 13 && gz <= 25)
      out[OFF_MAPS + ((size_t)(b*4 + 0) * LM + xs) * LM + ys] = 1.0f;
  }
}

// ---- fallback-only kernels (first[] aliased into maps region) ----
__global__ __launch_bounds__(256) void copy_maps(const float* __restrict__ map_last,
                                                 float* __restrict__ out_maps) {
  int i = blockIdx.x * blockDim.x + threadIdx.x;
  if (i < NC)
    *(float4*)(out_maps + (size_t)i * 4) = *(const float4*)(map_last + (size_t)i * 4);
}

__global__ __launch_bounds__(256) void scatter_maps(const float* __restrict__ out_coords,
                                                    const float* __restrict__ rep_flags,
                                                    float* __restrict__ out_maps) {
  int gid = blockIdx.x * blockDim.x + threadIdx.x;
  if (gid >= BSZ * NPIX) return;
  if (rep_flags[gid] == 0.0f) return;
  int b = gid / NPIX;
  float4 nc = *(const float4*)(out_coords + (size_t)gid * 4);
  int gx = (int)nc.y, gy = (int)nc.z, gz = (int)nc.w;
  int xs = min(max(gx, 0), LM - 1);
  int ys = min(max(gy, 0), LM - 1);
  out_maps[((size_t)(b*4 + 1) * LM + xs) * LM + ys] = 1.0f;
  if (gz >= 13 && gz <= 25)
    out_maps[((size_t)(b*4 + 0) * LM + xs) * LM + ys] = 1.0f;
}

extern "C" void kernel_launch(void* const* d_in, const int* in_sizes, int n_in,
                              void* d_out, int out_size, void* d_ws, size_t ws_size,
                              hipStream_t stream) {
  const float* obs        = (const float*)d_in[0];
  const float* pose_obs   = (const float*)d_in[1];
  const float* poses_last = (const float*)d_in[4];
  const float* map_last   = (const float*)d_in[5];
  float* out = (float*)d_out;

  const size_t FIRST_BYTES = (size_t)BSZ * NVOXB * sizeof(int);  // 25.6 MB
  bool use_ws = ws_size >= FIRST_BYTES + 4096;
  float* params = (float*)d_ws;
  int*   first  = use_ws ? (int*)((char*)d_ws + 4096) : (int*)(out + OFF_MAPS);

  float focf = (float)((double)WW / 2.0 / tan(39.5 * (M_PI / 180.0)));
  float rfoc = (float)(1.0 / (double)focf);

  hipLaunchKernelGGL(vox_store_pose, dim3(VOXBLK), dim3(256), 0, stream,
                     obs, first, rfoc, pose_obs, poses_last, out + OFF_POSES, params);
  if (use_ws) {
    hipLaunchKernelGGL(vox_refine_copy, dim3(VOXBLK + NCBLK), dim3(256), 0, stream,
                       obs, first, rfoc, map_last, out + OFF_MAPS, 1);
    hipLaunchKernelGGL(fused_kernel, dim3(BSZ * NPIX / 256), dim3(256), 0, stream,
                       obs, first, params, out, rfoc, 1);
  } else {
    hipLaunchKernelGGL(vox_refine_copy, dim3(VOXBLK), dim3(256), 0, stream,
                       obs, first, rfoc, map_last, out + OFF_MAPS, 0);
    hipLaunchKernelGGL(fused_kernel, dim3(BSZ * NPIX / 256), dim3(256), 0, stream,
                       obs, first, params, out, rfoc, 0);
    hipLaunchKernelGGL(copy_maps, dim3((NC + 255) / 256), dim3(256), 0, stream,
                       map_last, out + OFF_MAPS);
    hipLaunchKernelGGL(scatter_maps, dim3((BSZ * NPIX + 255) / 256), dim3(256), 0, stream,
                       out + OFF_COORDS, out + OFF_REP, out + OFF_MAPS);
  }
}